// Round 16
// baseline (2205.962 us; speedup 1.0000x reference)
//
#include <hip/hip_runtime.h>
#include <hip/hip_bf16.h>

typedef short bf16x8 __attribute__((ext_vector_type(8)));
typedef float f32x4 __attribute__((ext_vector_type(4)));
typedef float f32x16 __attribute__((ext_vector_type(16)));
typedef unsigned int u32x4 __attribute__((ext_vector_type(4)));
typedef unsigned int u32x2 __attribute__((ext_vector_type(2)));

typedef __attribute__((address_space(1))) void gvoid;
typedef __attribute__((address_space(3))) void lvoid;

__device__ __forceinline__ short f2b(float f) {
  __hip_bfloat16 h = __float2bfloat16(f);
  return __builtin_bit_cast(short, h);
}

__device__ __forceinline__ f32x4 mfma16(bf16x8 a, bf16x8 b, f32x4 c) {
  return __builtin_amdgcn_mfma_f32_16x16x32_bf16(a, b, c, 0, 0, 0);
}

__device__ __forceinline__ f32x16 mfma32(bf16x8 a, bf16x8 b, f32x16 c) {
  return __builtin_amdgcn_mfma_f32_32x32x16_bf16(a, b, c, 0, 0, 0);
}

__device__ __forceinline__ unsigned cvtpk(float lo, float hi) {
  unsigned r;
  asm("v_cvt_pk_bf16_f32 %0, %1, %2" : "=v"(r) : "v"(lo), "v"(hi));
  return r;
}

__device__ __forceinline__ void gload16(const void* g, void* l) {
  __builtin_amdgcn_global_load_lds((const gvoid*)g, (lvoid*)l, 16, 0, 0);
}

__device__ __forceinline__ int xcd_bijective(int lin, int nwg) {
  const int xcd = lin & 7, idx = lin >> 3;
  const int q0 = nwg >> 3, r0 = nwg & 7;
  return (xcd < r0) ? xcd * (q0 + 1) + idx
                    : r0 * (q0 + 1) + (xcd - r0) * q0 + idx;
}

// ---------------------------------------------------------------- weights
__global__ __launch_bounds__(256) void convT_k(const float* __restrict__ src,
                                               short* __restrict__ dst, int K,
                                               int N, int scale_cols,
                                               float scale) {
  int idx = blockIdx.x * 256 + threadIdx.x;
  if (idx >= N * K) return;
  int n = idx / K, k = idx % K;
  float v = src[(size_t)k * N + n];
  if (n < scale_cols) v *= scale;
  dst[idx] = f2b(v);
}

__global__ __launch_bounds__(256) void scale_bias_k(const float* __restrict__ src,
                                                    float* __restrict__ dst,
                                                    int n, int scale_cols,
                                                    float scale) {
  int i = blockIdx.x * 256 + threadIdx.x;
  if (i >= n) return;
  dst[i] = src[i] * (i < scale_cols ? scale : 1.f);
}

// Rel-pos bias + shift mask table, TRANSPOSED: tbl[cls][h][query][key].
__global__ __launch_bounds__(256) void biasmask_k(const float* __restrict__ rpb,
                                                  float* __restrict__ tbl) {
  int idx = blockIdx.x * 256 + threadIdx.x;  // < 4*12*64*64
  int key = idx & 63, q = (idx >> 6) & 63;
  int hc = idx >> 12;  // cls*12 + h
  int h = hc % 12, cls = hc / 12;
  float v;
  if (q >= 49 || key >= 49) {
    v = -1e4f;
  } else {
    int i1 = q / 7, j1 = q % 7, i2 = key / 7, j2 = key % 7;
    v = rpb[(size_t)((i1 - i2 + 6) * 13 + (j1 - j2 + 6)) * 12 + h];
    int clsh = cls >> 1, clsw = cls & 1;
    int rq = (clsh ? 1 + (i1 >= 4) : 0) * 3 + (clsw ? 1 + (j1 >= 4) : 0);
    int rk = (clsh ? 1 + (i2 >= 4) : 0) * 3 + (clsw ? 1 + (j2 >= 4) : 0);
    if (rq != rk) v -= 100.f;
  }
  tbl[idx] = v;
}

// ---------------------------------------------------------------- layernorm
template <bool GATHER>
__device__ __forceinline__ void ln_body(const float* __restrict__ x,
                                        const float* __restrict__ gw,
                                        const float* __restrict__ bw,
                                        short* __restrict__ out) {
  const int lane = threadIdx.x & 63;
  const int t = (blockIdx.x << 2) + (threadIdx.x >> 6);
  size_t srow;
  if (GATHER) {
    int bb = t / 12544, rm2 = t % 12544;
    int wi = rm2 / 49, nn = rm2 % 49;
    int wh = wi >> 4, ww = wi & 15;
    int ii = nn / 7, jj = nn % 7;
    int rr = wh * 7 + ii + 3; if (rr >= 112) rr -= 112;
    int cc = ww * 7 + jj + 3; if (cc >= 112) cc -= 112;
    srow = ((size_t)bb * 12544 + rr * 112 + cc) * 384;
  } else {
    srow = (size_t)t * 384;
  }
  const float2* src = (const float2*)(x + srow);
  const float2* g2 = (const float2*)gw;
  const float2* b2 = (const float2*)bw;
  float2 u[3];
  float s = 0.f, ss = 0.f;
#pragma unroll
  for (int k = 0; k < 3; ++k) {
    u[k] = src[lane + (k << 6)];
    s += u[k].x + u[k].y;
    ss += u[k].x * u[k].x + u[k].y * u[k].y;
  }
#pragma unroll
  for (int m = 1; m < 64; m <<= 1) {
    s += __shfl_xor(s, m, 64);
    ss += __shfl_xor(ss, m, 64);
  }
  const float mean = s * (1.f / 384.f);
  const float var = ss * (1.f / 384.f) - mean * mean;
  const float rstd = rsqrtf(var + 1e-5f);
  unsigned* o = (unsigned*)(out + (size_t)t * 384);
#pragma unroll
  for (int k = 0; k < 3; ++k) {
    int c = lane + (k << 6);
    float2 gv = g2[c], bv = b2[c];
    unsigned lo = (unsigned short)f2b((u[k].x - mean) * rstd * gv.x + bv.x);
    unsigned hi = (unsigned short)f2b((u[k].y - mean) * rstd * gv.y + bv.y);
    o[c] = lo | (hi << 16);
  }
}

__global__ __launch_bounds__(256) void ln1_k(const float* __restrict__ x,
                                             const float* __restrict__ gw,
                                             const float* __restrict__ bw,
                                             short* __restrict__ out) {
  ln_body<true>(x, gw, bw, out);
}
__global__ __launch_bounds__(256) void ln2_k(const float* __restrict__ x,
                                             const float* __restrict__ gw,
                                             const float* __restrict__ bw,
                                             short* __restrict__ out) {
  ln_body<false>(x, gw, bw, out);
}

// ---------------------------------------------------------------- epilogue
template <int EPI>
__device__ __forceinline__ void epi_store(int grow, int gcol, int ldo,
                                          f32x4 av, f32x4 bq,
                                          short* __restrict__ outh,
                                          float* __restrict__ outf,
                                          const float* __restrict__ resid) {
  size_t orow;
  if constexpr (EPI == 2) {
    int bb = grow / 12544, rm2 = grow % 12544;
    int wi = rm2 / 49, nn = rm2 % 49;
    int wh = wi >> 4, ww = wi & 15;
    int ii = nn / 7, jj = nn % 7;
    int rr = wh * 7 + ii + 3; if (rr >= 112) rr -= 112;
    int cc = ww * 7 + jj + 3; if (cc >= 112) cc -= 112;
    orow = ((size_t)bb * 12544 + rr * 112 + cc) * 384;
  } else {
    orow = (size_t)grow * (size_t)ldo;
  }
  float v[4];
#pragma unroll
  for (int j = 0; j < 4; ++j) v[j] = av[j] + bq[j];
  if constexpr (EPI == 0) {
    u32x2 u = {cvtpk(v[0], v[1]), cvtpk(v[2], v[3])};
    *(u32x2*)&outh[orow + gcol] = u;
  } else if constexpr (EPI == 1) {
#pragma unroll
    for (int j = 0; j < 4; ++j)
      v[j] = 0.5f * v[j] * (1.f + erff(v[j] * 0.70710678118f));
    u32x2 u = {cvtpk(v[0], v[1]), cvtpk(v[2], v[3])};
    *(u32x2*)&outh[orow + gcol] = u;
  } else if constexpr (EPI == 2) {
    f32x4 r = *(const f32x4*)&resid[orow + gcol];
#pragma unroll
    for (int j = 0; j < 4; ++j) r[j] += v[j];
    *(f32x4*)&outf[orow + gcol] = r;
  } else {
    f32x4 o = *(f32x4*)&outf[orow + gcol];
#pragma unroll
    for (int j = 0; j < 4; ++j) o[j] += v[j];
    *(f32x4*)&outf[orow + gcol] = o;
  }
}

// ---------------------------------------------------------------- GEMM A
// r12 geometry: 128x128 tile, BK=64, 512 thr / 8 waves (2x4), wave tile
// 64x32, static dbuf 64KB, zero-conflict swizzle. Best for K=1536 (fc2).
template <int EPI>
__device__ __forceinline__ void gemm_bodyA(
    const short* __restrict__ A, int lda, const short* __restrict__ BT,
    int ldb, const float* __restrict__ bias, int K, short* __restrict__ outh,
    int ldo, float* __restrict__ outf, const float* __restrict__ resid) {
  __shared__ __align__(16) short A0s[8192], B0s[8192];
  __shared__ __align__(16) short A1s[8192], B1s[8192];
  const int tid = threadIdx.x;
  const int gx = gridDim.x;
  int lin = xcd_bijective(blockIdx.y * gx + blockIdx.x, gx * gridDim.y);
  const int m0 = (lin / gx) << 7, n0 = (lin % gx) << 7;
  const int lane = tid & 63;
  const int wave = tid >> 6;
  const int wr = (wave >> 2) << 6;
  const int wc = (wave & 3) << 5;
  const int g = lane >> 4, q = lane & 15;
  const int q7 = q & 7;
  const int rd0 = ((g) ^ q7) << 3;
  const int rd1 = ((4 + g) ^ q7) << 3;
  const int cswz = ((tid & 7) ^ ((tid >> 3) & 7)) << 3;
  const int ldst = tid << 3;

  f32x4 acc[4][2];
#pragma unroll
  for (int i = 0; i < 4; ++i)
#pragma unroll
    for (int j = 0; j < 2; ++j) acc[i][j] = (f32x4){0.f, 0.f, 0.f, 0.f};

  const short* Abase = A + (size_t)(m0 + (tid >> 3)) * lda + cswz;
  const short* Bbase = BT + (size_t)(n0 + (tid >> 3)) * ldb + cswz;

#define STAGE(kt, DA, DB)                                        \
  do {                                                           \
    gload16(Abase + (kt), &DA[ldst]);                            \
    gload16(Abase + (size_t)64 * lda + (kt), &DA[4096 + ldst]);  \
    gload16(Bbase + (kt), &DB[ldst]);                            \
    gload16(Bbase + (size_t)64 * ldb + (kt), &DB[4096 + ldst]);  \
  } while (0)

#define COMPUTE(SA, SB)                                                       \
  do {                                                                        \
    _Pragma("unroll") for (int kk = 0; kk < 2; ++kk) {                        \
      const int rdo = kk ? rd1 : rd0;                                         \
      bf16x8 af[4], bfv[2];                                                   \
      _Pragma("unroll") for (int mi = 0; mi < 4; ++mi)                        \
          af[mi] = *(const bf16x8*)&SA[(wr + mi * 16 + q) * 64 + rdo];        \
      _Pragma("unroll") for (int ni = 0; ni < 2; ++ni)                        \
          bfv[ni] = *(const bf16x8*)&SB[(wc + ni * 16 + q) * 64 + rdo];       \
      _Pragma("unroll") for (int mi = 0; mi < 4; ++mi)                        \
          _Pragma("unroll") for (int ni = 0; ni < 2; ++ni)                    \
              acc[mi][ni] = mfma16(bfv[ni], af[mi], acc[mi][ni]);             \
    }                                                                         \
  } while (0)

  const int nt = K >> 6;  // 24: even
  STAGE(0, A0s, B0s);
  __syncthreads();
  for (int t = 0; t < nt; t += 2) {
    STAGE((t + 1) << 6, A1s, B1s);
    COMPUTE(A0s, B0s);
    __syncthreads();
    if (t + 2 < nt) STAGE((t + 2) << 6, A0s, B0s);
    COMPUTE(A1s, B1s);
    __syncthreads();
  }
#undef STAGE
#undef COMPUTE

  f32x4 bq[2];
#pragma unroll
  for (int ni = 0; ni < 2; ++ni)
    bq[ni] = bias ? *(const f32x4*)&bias[n0 + wc + ni * 16 + g * 4]
                  : (f32x4){0.f, 0.f, 0.f, 0.f};

#pragma unroll
  for (int mi = 0; mi < 4; ++mi) {
    const int grow = m0 + wr + mi * 16 + q;
#pragma unroll
    for (int ni = 0; ni < 2; ++ni)
      epi_store<EPI>(grow, n0 + wc + ni * 16 + g * 4, ldo, acc[mi][ni],
                     bq[ni], outh, outf, resid);
  }
}

// ---------------------------------------------------------------- GEMM B
// r13 geometry: 256x128 tile, BK=32, 512 thr / 8 waves (4x2), wave tile
// 64x64, static dbuf 48KB, balanced swizzle. Best for K=384 GEMMs.
// r16: MULTI-M-TILE persistence (MT=4): each block handles 4 consecutive
// 256-row tiles; the flattened staging loads tile it+1's k=0 in tile
// it's tail slot, so the dbuf pipeline never drains across tiles and
// each epilogue's stores overlap the next tile's staging. nt=12 (even)
// keeps A0/A1 parity identical across tiles. B-panel reused 4x/block.
template <int EPI>
__device__ __forceinline__ void gemm_bodyB(
    const short* __restrict__ A, int lda, const short* __restrict__ BT,
    int ldb, const float* __restrict__ bias, int K, short* __restrict__ outh,
    int ldo, float* __restrict__ outf, const float* __restrict__ resid) {
  __shared__ __align__(16) short A0s[8192], B0s[4096];
  __shared__ __align__(16) short A1s[8192], B1s[4096];
  const int tid = threadIdx.x;
  const int gx = gridDim.x;
  int lin = xcd_bijective(blockIdx.y * gx + blockIdx.x, gx * gridDim.y);
  const int mt0 = (lin / gx) << 10;  // 4 tiles x 256 rows
  const int n0 = (lin % gx) << 7;
  const int lane = tid & 63;
  const int wave = tid >> 6;
  const int wr = (wave >> 1) << 6;
  const int wc = (wave & 1) << 6;
  const int g = lane >> 4, q = lane & 15;
  const int rdo = ((g ^ ((q >> 1) & 3)) << 3);
  const int gc = ((tid & 3) ^ ((tid >> 3) & 3)) << 3;
  const int ldst = tid << 3;
  const size_t mstride = (size_t)256 * lda;

  f32x4 acc[4][4];

  const short* Ab = A + (size_t)(mt0 + (tid >> 2)) * lda + gc;
  const short* Bbase = BT + (size_t)(n0 + (tid >> 2)) * ldb + gc;

#define STAGEI(ab, kt, DA, DB)                                 \
  do {                                                         \
    gload16((ab) + (kt), &DA[ldst]);                           \
    gload16((ab) + (size_t)128 * lda + (kt), &DA[4096 + ldst]);\
    gload16(Bbase + (kt), &DB[ldst]);                          \
  } while (0)

#define COMPUTE(SA, SB)                                                       \
  do {                                                                        \
    bf16x8 af[4], bfv[4];                                                     \
    _Pragma("unroll") for (int mi = 0; mi < 4; ++mi)                          \
        af[mi] = *(const bf16x8*)&SA[(wr + mi * 16 + q) * 32 + rdo];          \
    _Pragma("unroll") for (int ni = 0; ni < 4; ++ni)                          \
        bfv[ni] = *(const bf16x8*)&SB[(wc + ni * 16 + q) * 32 + rdo];         \
    _Pragma("unroll") for (int mi = 0; mi < 4; ++mi)                          \
        _Pragma("unroll") for (int ni = 0; ni < 4; ++ni)                      \
            acc[mi][ni] = mfma16(bfv[ni], af[mi], acc[mi][ni]);               \
  } while (0)

  const int nt = K >> 5;  // 12 for all B users

  f32x4 bq[4];
#pragma unroll
  for (int ni = 0; ni < 4; ++ni)
    bq[ni] = bias ? *(const f32x4*)&bias[n0 + wc + ni * 16 + g * 4]
                  : (f32x4){0.f, 0.f, 0.f, 0.f};

  STAGEI(Ab, 0, A0s, B0s);
  __syncthreads();
  for (int it = 0; it < 4; ++it) {
#pragma unroll
    for (int i = 0; i < 4; ++i)
#pragma unroll
      for (int j = 0; j < 4; ++j) acc[i][j] = (f32x4){0.f, 0.f, 0.f, 0.f};

    for (int t = 0; t < nt; t += 2) {
      STAGEI(Ab, (t + 1) << 5, A1s, B1s);
      COMPUTE(A0s, B0s);
      __syncthreads();
      if (t + 2 < nt) STAGEI(Ab, (t + 2) << 5, A0s, B0s);
      else if (it + 1 < 4) STAGEI(Ab + mstride, 0, A0s, B0s);
      COMPUTE(A1s, B1s);
      __syncthreads();
    }

    const int m0 = mt0 + (it << 8);
#pragma unroll
    for (int mi = 0; mi < 4; ++mi) {
      const int grow = m0 + wr + mi * 16 + q;
#pragma unroll
      for (int ni = 0; ni < 4; ++ni)
        epi_store<EPI>(grow, n0 + wc + ni * 16 + g * 4, ldo, acc[mi][ni],
                       bq[ni], outh, outf, resid);
    }
    Ab += mstride;
  }
#undef STAGEI
#undef COMPUTE
}

#define GEMM_WRAP(NAME, BODY, EPI)                                             \
  __global__ __launch_bounds__(512) void NAME(                                 \
      const short* __restrict__ A, int lda, const short* __restrict__ BT,      \
      int ldb, const float* __restrict__ bias, int K,                          \
      short* __restrict__ outh, int ldo, float* __restrict__ outf,             \
      const float* __restrict__ resid) {                                       \
    BODY<EPI>(A, lda, BT, ldb, bias, K, outh, ldo, outf, resid);               \
  }
GEMM_WRAP(gemm_qkv_k, gemm_bodyB, 0)
GEMM_WRAP(gemm_proj_k, gemm_bodyB, 2)
GEMM_WRAP(gemm_fc1_k, gemm_bodyB, 1)
GEMM_WRAP(gemm_fc2_k, gemm_bodyA, 3)

// ---------------------------------------------------------------- attention
// One wave per (window, head), 8 waves/block (512 thr). Swapped QK^T via
// mfma_32x32x16; in-register softmax; cvt_pk + shfl_xor(32) assembles PV
// A-frags (T12); bias+mask from TRANSPOSED table read as f32x4; V via
// per-wave private LDS transpose (coalesced loads, 2-way-free reads).
__global__ __launch_bounds__(512) void attn_k(const short* __restrict__ qkv,
                                              const float* __restrict__ tbl,
                                              short* __restrict__ out) {
  __shared__ __align__(16) short Vs[8][2048];
  const int lane = threadIdx.x & 63;
  const int wave = threadIdx.x >> 6;
  const int task = blockIdx.x * 8 + wave;
  const int win = task / 12;
  const int h = task - win * 12;
  const int wh = (win >> 4) & 15, ww = win & 15;
  const int cls = ((wh == 15) ? 2 : 0) + ((ww == 15) ? 1 : 0);
  const int l31 = lane & 31, h5 = lane >> 5;
  const size_t tokbase = (size_t)win * 49;
  const short* base = qkv + tokbase * 1152 + h * 32;
  const bf16x8 zero8 = {0, 0, 0, 0, 0, 0, 0, 0};
  short* vsw = &Vs[wave][0];

  bf16x8 kf[2][2];
#pragma unroll
  for (int mi = 0; mi < 2; ++mi) {
    int row = l31 + 32 * mi;
#pragma unroll
    for (int s = 0; s < 2; ++s)
      kf[mi][s] = (row < 49)
                      ? *(const bf16x8*)(base + (size_t)row * 1152 + 384 +
                                         16 * s + 8 * h5)
                      : zero8;
  }

  // V: coalesced row loads -> LDS [key][d] -> transposed scalar reads
#pragma unroll
  for (int it = 0; it < 2; ++it) {
    const int key = 32 * it + (lane >> 1);
    const int dch = (lane & 1) << 4;
    bf16x8 v0 = zero8, v1 = zero8;
    if (key < 49) {
      const short* vp = base + (size_t)key * 1152 + 768 + dch;
      v0 = *(const bf16x8*)vp;
      v1 = *(const bf16x8*)(vp + 8);
    }
    *(bf16x8*)&vsw[key * 32 + dch] = v0;
    *(bf16x8*)&vsw[key * 32 + dch + 8] = v1;
  }
  asm volatile("s_waitcnt lgkmcnt(0)" ::: "memory");
  __builtin_amdgcn_sched_barrier(0);
  bf16x8 vf[4];
#pragma unroll
  for (int kt = 0; kt < 4; ++kt)
#pragma unroll
    for (int e = 0; e < 8; ++e)
      vf[kt][e] = vsw[(16 * kt + 8 * h5 + e) * 32 + l31];

  const float* tb = tbl + ((size_t)(cls * 12 + h) << 12);

#pragma unroll
  for (int ni = 0; ni < 2; ++ni) {
    bf16x8 qf[2];
    int qrow = l31 + 32 * ni;
#pragma unroll
    for (int s = 0; s < 2; ++s)
      qf[s] = (qrow < 49)
                  ? *(const bf16x8*)(base + (size_t)qrow * 1152 + 16 * s +
                                     8 * h5)
                  : zero8;
    f32x16 st[2];
#pragma unroll
    for (int mi = 0; mi < 2; ++mi) {
      st[mi] = mfma32(kf[mi][0], qf[0], (f32x16)(0.f));
      st[mi] = mfma32(kf[mi][1], qf[1], st[mi]);
    }
#pragma unroll
    for (int mi = 0; mi < 2; ++mi) {
      const float* bp = tb + (size_t)(32 * ni + l31) * 64 + 32 * mi + 4 * h5;
#pragma unroll
      for (int j = 0; j < 4; ++j) {
        f32x4 b4 = *(const f32x4*)(bp + 8 * j);
#pragma unroll
        for (int e = 0; e < 4; ++e) st[mi][4 * j + e] += b4[e];
      }
    }
    float mx = st[0][0];
#pragma unroll
    for (int r = 1; r < 16; ++r) mx = fmaxf(mx, st[0][r]);
#pragma unroll
    for (int r = 0; r < 16; ++r) mx = fmaxf(mx, st[1][r]);
    mx = fmaxf(mx, __shfl_xor(mx, 32, 64));
    float sm = 0.f;
#pragma unroll
    for (int mi = 0; mi < 2; ++mi)
#pragma unroll
      for (int r = 0; r < 16; ++r) {
        float e = __expf(st[mi][r] - mx);
        st[mi][r] = e;
        sm += e;
      }
    sm += __shfl_xor(sm, 32, 64);
    const float rinv = 1.f / sm;
#pragma unroll
    for (int mi = 0; mi < 2; ++mi)
#pragma unroll
      for (int r = 0; r < 16; ++r) st[mi][r] *= rinv;

    f32x16 acc = (f32x16)(0.f);
#pragma unroll
    for (int kt = 0; kt < 4; ++kt) {
      const int mi = kt >> 1, b8 = (kt & 1) * 8;
      unsigned q0l = cvtpk(st[mi][b8 + 0], st[mi][b8 + 1]);
      unsigned q0h = cvtpk(st[mi][b8 + 2], st[mi][b8 + 3]);
      unsigned q1l = cvtpk(st[mi][b8 + 4], st[mi][b8 + 5]);
      unsigned q1h = cvtpk(st[mi][b8 + 6], st[mi][b8 + 7]);
      unsigned sl = h5 ? q0l : q1l, sh = h5 ? q0h : q1h;
      unsigned kl = h5 ? q1l : q0l, kh = h5 ? q1h : q0h;
      unsigned rl = (unsigned)__shfl_xor((int)sl, 32, 64);
      unsigned rh = (unsigned)__shfl_xor((int)sh, 32, 64);
      u32x4 fr;
      fr[0] = h5 ? rl : kl;
      fr[1] = h5 ? rh : kh;
      fr[2] = h5 ? kl : rl;
      fr[3] = h5 ? kh : rh;
      acc = mfma32(__builtin_bit_cast(bf16x8, fr), vf[kt], acc);
    }
#pragma unroll
    for (int r = 0; r < 16; ++r) {
      int query = 32 * ni + (r & 3) + 8 * (r >> 2) + 4 * h5;
      if (ni == 0 || query < 49)
        out[(tokbase + query) * 384 + h * 32 + l31] = f2b(acc[r]);
    }
  }
}

// ---------------------------------------------------------------- launch
extern "C" void kernel_launch(void* const* d_in, const int* in_sizes, int n_in,
                              void* d_out, int out_size, void* d_ws,
                              size_t ws_size, hipStream_t stream) {
  const float* x = (const float*)d_in[0];
  const float* n1g = (const float*)d_in[1];
  const float* n1b = (const float*)d_in[2];
  const float* qkvw = (const float*)d_in[3];
  const float* qkvb = (const float*)d_in[4];
  const float* projw = (const float*)d_in[5];
  const float* projb = (const float*)d_in[6];
  const float* rpb = (const float*)d_in[7];
  const float* n2g = (const float*)d_in[8];
  const float* n2b = (const float*)d_in[9];
  const float* fc1w = (const float*)d_in[10];
  const float* fc1b = (const float*)d_in[11];
  const float* fc2w = (const float*)d_in[12];
  const float* fc2b = (const float*)d_in[13];
  float* out = (float*)d_out;

  char* ws = (char*)d_ws;
  short* w_qkvT = (short*)(ws + 0);            // 884736 B
  short* w_projT = (short*)(ws + 884736);      // 294912 B
  short* w_fc1T = (short*)(ws + 1179648);      // 1179648 B
  short* w_fc2T = (short*)(ws + 2359296);      // 1179648 B
  float* w_qb = (float*)(ws + 3538944);        // 4608 B
  float* tbl = (float*)(ws + 3543552);         // 786432 B
  const size_t o_qkv = 4329984;
  short* qkvbuf = (short*)(ws + o_qkv);        // 462422016 B
  const size_t o_hwin = o_qkv + 462422016ull;
  short* hwin = (short*)(ws + o_hwin);         // 154140672 B
  short* fc1c = hwin;  // MLP slab overlays hwin (dead after proj)
  short* h2 = qkvbuf;  // LN2 out overlays qkv buffer (dead after attn)

  const float qscale = 0.17677669529663687f;

  convT_k<<<(442368 + 255) / 256, 256, 0, stream>>>(qkvw, w_qkvT, 384, 1152, 384, qscale);
  convT_k<<<(147456 + 255) / 256, 256, 0, stream>>>(projw, w_projT, 384, 384, 0, 1.f);
  convT_k<<<(589824 + 255) / 256, 256, 0, stream>>>(fc1w, w_fc1T, 384, 1536, 0, 1.f);
  convT_k<<<(589824 + 255) / 256, 256, 0, stream>>>(fc2w, w_fc2T, 1536, 384, 0, 1.f);
  scale_bias_k<<<5, 256, 0, stream>>>(qkvb, w_qb, 1152, 384, qscale);
  biasmask_k<<<768, 256, 0, stream>>>(rpb, tbl);

  ln1_k<<<50176, 256, 0, stream>>>(x, n1g, n1b, hwin);
  // K=384 GEMMs: geometry B (256x128, BK=32), MT=4 persistent blocks
  gemm_qkv_k<<<dim3(9, 196), 512, 0, stream>>>(hwin, 384, w_qkvT, 384, w_qb,
                                               384, qkvbuf, 1152, nullptr,
                                               nullptr);
  attn_k<<<6144, 512, 0, stream>>>(qkvbuf, tbl, hwin);
  gemm_proj_k<<<dim3(3, 196), 512, 0, stream>>>(hwin, 384, w_projT, 384,
                                                projb, 384, nullptr, 384, out,
                                                x);
  ln2_k<<<50176, 256, 0, stream>>>(out, n2g, n2b, h2);
  // MLP over 4 M-slabs of 50176 rows: fc1 geometry B MT=4 (K=384), fc2
  // geometry A (K=1536). Slab L3-resident; out RMW'd once.
  for (int s = 0; s < 4; ++s) {
    const size_t ro = (size_t)s * 50176;
    gemm_fc1_k<<<dim3(12, 49), 512, 0, stream>>>(
        h2 + ro * 384, 384, w_fc1T, 384, fc1b, 384, fc1c, 1536, nullptr,
        nullptr);
    gemm_fc2_k<<<dim3(3, 392), 512, 0, stream>>>(
        fc1c, 1536, w_fc2T, 1536, fc2b, 1536, nullptr, 384, out + ro * 384,
        nullptr);
  }
}

// Round 17
// 1791.482 us; speedup vs baseline: 1.2314x; 1.2314x over previous
//
#include <hip/hip_runtime.h>
#include <hip/hip_bf16.h>

typedef short bf16x8 __attribute__((ext_vector_type(8)));
typedef float f32x4 __attribute__((ext_vector_type(4)));
typedef float f32x16 __attribute__((ext_vector_type(16)));
typedef unsigned int u32x4 __attribute__((ext_vector_type(4)));
typedef unsigned int u32x2 __attribute__((ext_vector_type(2)));

typedef __attribute__((address_space(1))) void gvoid;
typedef __attribute__((address_space(3))) void lvoid;

__device__ __forceinline__ short f2b(float f) {
  __hip_bfloat16 h = __float2bfloat16(f);
  return __builtin_bit_cast(short, h);
}

__device__ __forceinline__ f32x4 mfma16(bf16x8 a, bf16x8 b, f32x4 c) {
  return __builtin_amdgcn_mfma_f32_16x16x32_bf16(a, b, c, 0, 0, 0);
}

__device__ __forceinline__ f32x16 mfma32(bf16x8 a, bf16x8 b, f32x16 c) {
  return __builtin_amdgcn_mfma_f32_32x32x16_bf16(a, b, c, 0, 0, 0);
}

__device__ __forceinline__ unsigned cvtpk(float lo, float hi) {
  unsigned r;
  asm("v_cvt_pk_bf16_f32 %0, %1, %2" : "=v"(r) : "v"(lo), "v"(hi));
  return r;
}

__device__ __forceinline__ void gload16(const void* g, void* l) {
  __builtin_amdgcn_global_load_lds((const gvoid*)g, (lvoid*)l, 16, 0, 0);
}

__device__ __forceinline__ int xcd_bijective(int lin, int nwg) {
  const int xcd = lin & 7, idx = lin >> 3;
  const int q0 = nwg >> 3, r0 = nwg & 7;
  return (xcd < r0) ? xcd * (q0 + 1) + idx
                    : r0 * (q0 + 1) + (xcd - r0) * q0 + idx;
}

// ---------------------------------------------------------------- weights
__global__ __launch_bounds__(256) void convT_k(const float* __restrict__ src,
                                               short* __restrict__ dst, int K,
                                               int N, int scale_cols,
                                               float scale) {
  int idx = blockIdx.x * 256 + threadIdx.x;
  if (idx >= N * K) return;
  int n = idx / K, k = idx % K;
  float v = src[(size_t)k * N + n];
  if (n < scale_cols) v *= scale;
  dst[idx] = f2b(v);
}

__global__ __launch_bounds__(256) void scale_bias_k(const float* __restrict__ src,
                                                    float* __restrict__ dst,
                                                    int n, int scale_cols,
                                                    float scale) {
  int i = blockIdx.x * 256 + threadIdx.x;
  if (i >= n) return;
  dst[i] = src[i] * (i < scale_cols ? scale : 1.f);
}

// Rel-pos bias + shift mask table, TRANSPOSED: tbl[cls][h][query][key].
__global__ __launch_bounds__(256) void biasmask_k(const float* __restrict__ rpb,
                                                  float* __restrict__ tbl) {
  int idx = blockIdx.x * 256 + threadIdx.x;  // < 4*12*64*64
  int key = idx & 63, q = (idx >> 6) & 63;
  int hc = idx >> 12;  // cls*12 + h
  int h = hc % 12, cls = hc / 12;
  float v;
  if (q >= 49 || key >= 49) {
    v = -1e4f;
  } else {
    int i1 = q / 7, j1 = q % 7, i2 = key / 7, j2 = key % 7;
    v = rpb[(size_t)((i1 - i2 + 6) * 13 + (j1 - j2 + 6)) * 12 + h];
    int clsh = cls >> 1, clsw = cls & 1;
    int rq = (clsh ? 1 + (i1 >= 4) : 0) * 3 + (clsw ? 1 + (j1 >= 4) : 0);
    int rk = (clsh ? 1 + (i2 >= 4) : 0) * 3 + (clsw ? 1 + (j2 >= 4) : 0);
    if (rq != rk) v -= 100.f;
  }
  tbl[idx] = v;
}

// ---------------------------------------------------------------- layernorm
template <bool GATHER>
__device__ __forceinline__ void ln_body(const float* __restrict__ x,
                                        const float* __restrict__ gw,
                                        const float* __restrict__ bw,
                                        short* __restrict__ out) {
  const int lane = threadIdx.x & 63;
  const int t = (blockIdx.x << 2) + (threadIdx.x >> 6);
  size_t srow;
  if (GATHER) {
    int bb = t / 12544, rm2 = t % 12544;
    int wi = rm2 / 49, nn = rm2 % 49;
    int wh = wi >> 4, ww = wi & 15;
    int ii = nn / 7, jj = nn % 7;
    int rr = wh * 7 + ii + 3; if (rr >= 112) rr -= 112;
    int cc = ww * 7 + jj + 3; if (cc >= 112) cc -= 112;
    srow = ((size_t)bb * 12544 + rr * 112 + cc) * 384;
  } else {
    srow = (size_t)t * 384;
  }
  const float2* src = (const float2*)(x + srow);
  const float2* g2 = (const float2*)gw;
  const float2* b2 = (const float2*)bw;
  float2 u[3];
  float s = 0.f, ss = 0.f;
#pragma unroll
  for (int k = 0; k < 3; ++k) {
    u[k] = src[lane + (k << 6)];
    s += u[k].x + u[k].y;
    ss += u[k].x * u[k].x + u[k].y * u[k].y;
  }
#pragma unroll
  for (int m = 1; m < 64; m <<= 1) {
    s += __shfl_xor(s, m, 64);
    ss += __shfl_xor(ss, m, 64);
  }
  const float mean = s * (1.f / 384.f);
  const float var = ss * (1.f / 384.f) - mean * mean;
  const float rstd = rsqrtf(var + 1e-5f);
  unsigned* o = (unsigned*)(out + (size_t)t * 384);
#pragma unroll
  for (int k = 0; k < 3; ++k) {
    int c = lane + (k << 6);
    float2 gv = g2[c], bv = b2[c];
    unsigned lo = (unsigned short)f2b((u[k].x - mean) * rstd * gv.x + bv.x);
    unsigned hi = (unsigned short)f2b((u[k].y - mean) * rstd * gv.y + bv.y);
    o[c] = lo | (hi << 16);
  }
}

__global__ __launch_bounds__(256) void ln1_k(const float* __restrict__ x,
                                             const float* __restrict__ gw,
                                             const float* __restrict__ bw,
                                             short* __restrict__ out) {
  ln_body<true>(x, gw, bw, out);
}
__global__ __launch_bounds__(256) void ln2_k(const float* __restrict__ x,
                                             const float* __restrict__ gw,
                                             const float* __restrict__ bw,
                                             short* __restrict__ out) {
  ln_body<false>(x, gw, bw, out);
}

// ---------------------------------------------------------------- epilogue
template <int EPI>
__device__ __forceinline__ void epi_store(int grow, int gcol, int ldo,
                                          f32x4 av, f32x4 bq,
                                          short* __restrict__ outh,
                                          float* __restrict__ outf,
                                          const float* __restrict__ resid) {
  size_t orow;
  if constexpr (EPI == 2) {
    int bb = grow / 12544, rm2 = grow % 12544;
    int wi = rm2 / 49, nn = rm2 % 49;
    int wh = wi >> 4, ww = wi & 15;
    int ii = nn / 7, jj = nn % 7;
    int rr = wh * 7 + ii + 3; if (rr >= 112) rr -= 112;
    int cc = ww * 7 + jj + 3; if (cc >= 112) cc -= 112;
    orow = ((size_t)bb * 12544 + rr * 112 + cc) * 384;
  } else {
    orow = (size_t)grow * (size_t)ldo;
  }
  float v[4];
#pragma unroll
  for (int j = 0; j < 4; ++j) v[j] = av[j] + bq[j];
  if constexpr (EPI == 0) {
    u32x2 u = {cvtpk(v[0], v[1]), cvtpk(v[2], v[3])};
    *(u32x2*)&outh[orow + gcol] = u;
  } else if constexpr (EPI == 1) {
#pragma unroll
    for (int j = 0; j < 4; ++j)
      v[j] = 0.5f * v[j] * (1.f + erff(v[j] * 0.70710678118f));
    u32x2 u = {cvtpk(v[0], v[1]), cvtpk(v[2], v[3])};
    *(u32x2*)&outh[orow + gcol] = u;
  } else if constexpr (EPI == 2) {
    f32x4 r = *(const f32x4*)&resid[orow + gcol];
#pragma unroll
    for (int j = 0; j < 4; ++j) r[j] += v[j];
    *(f32x4*)&outf[orow + gcol] = r;
  } else {
    f32x4 o = *(f32x4*)&outf[orow + gcol];
#pragma unroll
    for (int j = 0; j < 4; ++j) o[j] += v[j];
    *(f32x4*)&outf[orow + gcol] = o;
  }
}

// ---------------------------------------------------------------- GEMM A
// 128x128 tile, BK=64, 512 thr / 8 waves (2x4), wave tile 64x32, static
// dbuf 64KB, zero-conflict swizzle. Best for K=1536 (fc2).
template <int EPI>
__device__ __forceinline__ void gemm_bodyA(
    const short* __restrict__ A, int lda, const short* __restrict__ BT,
    int ldb, const float* __restrict__ bias, int K, short* __restrict__ outh,
    int ldo, float* __restrict__ outf, const float* __restrict__ resid) {
  __shared__ __align__(16) short A0s[8192], B0s[8192];
  __shared__ __align__(16) short A1s[8192], B1s[8192];
  const int tid = threadIdx.x;
  const int gx = gridDim.x;
  int lin = xcd_bijective(blockIdx.y * gx + blockIdx.x, gx * gridDim.y);
  const int m0 = (lin / gx) << 7, n0 = (lin % gx) << 7;
  const int lane = tid & 63;
  const int wave = tid >> 6;
  const int wr = (wave >> 2) << 6;
  const int wc = (wave & 3) << 5;
  const int g = lane >> 4, q = lane & 15;
  const int q7 = q & 7;
  const int rd0 = ((g) ^ q7) << 3;
  const int rd1 = ((4 + g) ^ q7) << 3;
  const int cswz = ((tid & 7) ^ ((tid >> 3) & 7)) << 3;
  const int ldst = tid << 3;

  f32x4 acc[4][2];
#pragma unroll
  for (int i = 0; i < 4; ++i)
#pragma unroll
    for (int j = 0; j < 2; ++j) acc[i][j] = (f32x4){0.f, 0.f, 0.f, 0.f};

  const short* Abase = A + (size_t)(m0 + (tid >> 3)) * lda + cswz;
  const short* Bbase = BT + (size_t)(n0 + (tid >> 3)) * ldb + cswz;

#define STAGE(kt, DA, DB)                                        \
  do {                                                           \
    gload16(Abase + (kt), &DA[ldst]);                            \
    gload16(Abase + (size_t)64 * lda + (kt), &DA[4096 + ldst]);  \
    gload16(Bbase + (kt), &DB[ldst]);                            \
    gload16(Bbase + (size_t)64 * ldb + (kt), &DB[4096 + ldst]);  \
  } while (0)

#define COMPUTE(SA, SB)                                                       \
  do {                                                                        \
    _Pragma("unroll") for (int kk = 0; kk < 2; ++kk) {                        \
      const int rdo = kk ? rd1 : rd0;                                         \
      bf16x8 af[4], bfv[2];                                                   \
      _Pragma("unroll") for (int mi = 0; mi < 4; ++mi)                        \
          af[mi] = *(const bf16x8*)&SA[(wr + mi * 16 + q) * 64 + rdo];        \
      _Pragma("unroll") for (int ni = 0; ni < 2; ++ni)                        \
          bfv[ni] = *(const bf16x8*)&SB[(wc + ni * 16 + q) * 64 + rdo];       \
      _Pragma("unroll") for (int mi = 0; mi < 4; ++mi)                        \
          _Pragma("unroll") for (int ni = 0; ni < 2; ++ni)                    \
              acc[mi][ni] = mfma16(bfv[ni], af[mi], acc[mi][ni]);             \
    }                                                                         \
  } while (0)

  const int nt = K >> 6;  // 24: even
  STAGE(0, A0s, B0s);
  __syncthreads();
  for (int t = 0; t < nt; t += 2) {
    STAGE((t + 1) << 6, A1s, B1s);
    COMPUTE(A0s, B0s);
    __syncthreads();
    if (t + 2 < nt) STAGE((t + 2) << 6, A0s, B0s);
    COMPUTE(A1s, B1s);
    __syncthreads();
  }
#undef STAGE
#undef COMPUTE

  f32x4 bq[2];
#pragma unroll
  for (int ni = 0; ni < 2; ++ni)
    bq[ni] = bias ? *(const f32x4*)&bias[n0 + wc + ni * 16 + g * 4]
                  : (f32x4){0.f, 0.f, 0.f, 0.f};

#pragma unroll
  for (int mi = 0; mi < 4; ++mi) {
    const int grow = m0 + wr + mi * 16 + q;
#pragma unroll
    for (int ni = 0; ni < 2; ++ni)
      epi_store<EPI>(grow, n0 + wc + ni * 16 + g * 4, ldo, acc[mi][ni],
                     bq[ni], outh, outf, resid);
  }
}

// ---------------------------------------------------------------- GEMM B
// 256x128 tile, BK=32, 512 thr / 8 waves (4x2), wave tile 64x64, static
// dbuf 48KB, balanced swizzle. Best for K=384 GEMMs (qkv/proj/fc1).
template <int EPI>
__device__ __forceinline__ void gemm_bodyB(
    const short* __restrict__ A, int lda, const short* __restrict__ BT,
    int ldb, const float* __restrict__ bias, int K, short* __restrict__ outh,
    int ldo, float* __restrict__ outf, const float* __restrict__ resid) {
  __shared__ __align__(16) short A0s[8192], B0s[4096];
  __shared__ __align__(16) short A1s[8192], B1s[4096];
  const int tid = threadIdx.x;
  const int gx = gridDim.x;
  int lin = xcd_bijective(blockIdx.y * gx + blockIdx.x, gx * gridDim.y);
  const int m0 = (lin / gx) << 8, n0 = (lin % gx) << 7;
  const int lane = tid & 63;
  const int wave = tid >> 6;
  const int wr = (wave >> 1) << 6;
  const int wc = (wave & 1) << 6;
  const int g = lane >> 4, q = lane & 15;
  const int rdo = ((g ^ ((q >> 1) & 3)) << 3);
  const int gc = ((tid & 3) ^ ((tid >> 3) & 3)) << 3;
  const int ldst = tid << 3;

  f32x4 acc[4][4];
#pragma unroll
  for (int i = 0; i < 4; ++i)
#pragma unroll
    for (int j = 0; j < 4; ++j) acc[i][j] = (f32x4){0.f, 0.f, 0.f, 0.f};

  const short* Abase = A + (size_t)(m0 + (tid >> 2)) * lda + gc;
  const short* Bbase = BT + (size_t)(n0 + (tid >> 2)) * ldb + gc;

#define STAGE(kt, DA, DB)                                         \
  do {                                                            \
    gload16(Abase + (kt), &DA[ldst]);                             \
    gload16(Abase + (size_t)128 * lda + (kt), &DA[4096 + ldst]);  \
    gload16(Bbase + (kt), &DB[ldst]);                             \
  } while (0)

#define COMPUTE(SA, SB)                                                       \
  do {                                                                        \
    bf16x8 af[4], bfv[4];                                                     \
    _Pragma("unroll") for (int mi = 0; mi < 4; ++mi)                          \
        af[mi] = *(const bf16x8*)&SA[(wr + mi * 16 + q) * 32 + rdo];          \
    _Pragma("unroll") for (int ni = 0; ni < 4; ++ni)                          \
        bfv[ni] = *(const bf16x8*)&SB[(wc + ni * 16 + q) * 32 + rdo];         \
    _Pragma("unroll") for (int mi = 0; mi < 4; ++mi)                          \
        _Pragma("unroll") for (int ni = 0; ni < 4; ++ni)                      \
            acc[mi][ni] = mfma16(bfv[ni], af[mi], acc[mi][ni]);               \
  } while (0)

  const int nt = K >> 5;  // 12: even
  STAGE(0, A0s, B0s);
  __syncthreads();
  for (int t = 0; t < nt; t += 2) {
    STAGE((t + 1) << 5, A1s, B1s);
    COMPUTE(A0s, B0s);
    __syncthreads();
    if (t + 2 < nt) STAGE((t + 2) << 5, A0s, B0s);
    COMPUTE(A1s, B1s);
    __syncthreads();
  }
#undef STAGE
#undef COMPUTE

  f32x4 bq[4];
#pragma unroll
  for (int ni = 0; ni < 4; ++ni)
    bq[ni] = bias ? *(const f32x4*)&bias[n0 + wc + ni * 16 + g * 4]
                  : (f32x4){0.f, 0.f, 0.f, 0.f};

#pragma unroll
  for (int mi = 0; mi < 4; ++mi) {
    const int grow = m0 + wr + mi * 16 + q;
#pragma unroll
    for (int ni = 0; ni < 4; ++ni)
      epi_store<EPI>(grow, n0 + wc + ni * 16 + g * 4, ldo, acc[mi][ni],
                     bq[ni], outh, outf, resid);
  }
}

#define GEMM_WRAP(NAME, BODY, EPI)                                             \
  __global__ __launch_bounds__(512) void NAME(                                 \
      const short* __restrict__ A, int lda, const short* __restrict__ BT,      \
      int ldb, const float* __restrict__ bias, int K,                          \
      short* __restrict__ outh, int ldo, float* __restrict__ outf,             \
      const float* __restrict__ resid) {                                       \
    BODY<EPI>(A, lda, BT, ldb, bias, K, outh, ldo, outf, resid);               \
  }
GEMM_WRAP(gemm_qkv_k, gemm_bodyB, 0)
GEMM_WRAP(gemm_proj_k, gemm_bodyB, 2)
GEMM_WRAP(gemm_fc1_k, gemm_bodyB, 1)
GEMM_WRAP(gemm_fc2_k, gemm_bodyA, 3)

// ---------------------------------------------------------------- attention
// One wave per (window, head), 4 waves/block. Swapped QK^T via
// mfma_32x32x16; in-register softmax; cvt_pk + shfl_xor(32) assembles PV
// A-frags (T12); bias+mask from TRANSPOSED table read as f32x4; V via
// per-wave private LDS transpose (coalesced loads, 2-way-free reads).
__global__ __launch_bounds__(256) void attn_k(const short* __restrict__ qkv,
                                              const float* __restrict__ tbl,
                                              short* __restrict__ out) {
  __shared__ __align__(16) short Vs[4][2048];
  const int lane = threadIdx.x & 63;
  const int wave = threadIdx.x >> 6;
  const int task = blockIdx.x * 4 + wave;
  const int win = task / 12;
  const int h = task - win * 12;
  const int wh = (win >> 4) & 15, ww = win & 15;
  const int cls = ((wh == 15) ? 2 : 0) + ((ww == 15) ? 1 : 0);
  const int l31 = lane & 31, h5 = lane >> 5;
  const size_t tokbase = (size_t)win * 49;
  const short* base = qkv + tokbase * 1152 + h * 32;
  const bf16x8 zero8 = {0, 0, 0, 0, 0, 0, 0, 0};
  short* vsw = &Vs[wave][0];

  bf16x8 kf[2][2];
#pragma unroll
  for (int mi = 0; mi < 2; ++mi) {
    int row = l31 + 32 * mi;
#pragma unroll
    for (int s = 0; s < 2; ++s)
      kf[mi][s] = (row < 49)
                      ? *(const bf16x8*)(base + (size_t)row * 1152 + 384 +
                                         16 * s + 8 * h5)
                      : zero8;
  }

  // V: coalesced row loads -> LDS [key][d] -> transposed scalar reads
#pragma unroll
  for (int it = 0; it < 2; ++it) {
    const int key = 32 * it + (lane >> 1);
    const int dch = (lane & 1) << 4;
    bf16x8 v0 = zero8, v1 = zero8;
    if (key < 49) {
      const short* vp = base + (size_t)key * 1152 + 768 + dch;
      v0 = *(const bf16x8*)vp;
      v1 = *(const bf16x8*)(vp + 8);
    }
    *(bf16x8*)&vsw[key * 32 + dch] = v0;
    *(bf16x8*)&vsw[key * 32 + dch + 8] = v1;
  }
  asm volatile("s_waitcnt lgkmcnt(0)" ::: "memory");
  __builtin_amdgcn_sched_barrier(0);
  bf16x8 vf[4];
#pragma unroll
  for (int kt = 0; kt < 4; ++kt)
#pragma unroll
    for (int e = 0; e < 8; ++e)
      vf[kt][e] = vsw[(16 * kt + 8 * h5 + e) * 32 + l31];

  const float* tb = tbl + ((size_t)(cls * 12 + h) << 12);

#pragma unroll
  for (int ni = 0; ni < 2; ++ni) {
    bf16x8 qf[2];
    int qrow = l31 + 32 * ni;
#pragma unroll
    for (int s = 0; s < 2; ++s)
      qf[s] = (qrow < 49)
                  ? *(const bf16x8*)(base + (size_t)qrow * 1152 + 16 * s +
                                     8 * h5)
                  : zero8;
    f32x16 st[2];
#pragma unroll
    for (int mi = 0; mi < 2; ++mi) {
      st[mi] = mfma32(kf[mi][0], qf[0], (f32x16)(0.f));
      st[mi] = mfma32(kf[mi][1], qf[1], st[mi]);
    }
#pragma unroll
    for (int mi = 0; mi < 2; ++mi) {
      const float* bp = tb + (size_t)(32 * ni + l31) * 64 + 32 * mi + 4 * h5;
#pragma unroll
      for (int j = 0; j < 4; ++j) {
        f32x4 b4 = *(const f32x4*)(bp + 8 * j);
#pragma unroll
        for (int e = 0; e < 4; ++e) st[mi][4 * j + e] += b4[e];
      }
    }
    float mx = st[0][0];
#pragma unroll
    for (int r = 1; r < 16; ++r) mx = fmaxf(mx, st[0][r]);
#pragma unroll
    for (int r = 0; r < 16; ++r) mx = fmaxf(mx, st[1][r]);
    mx = fmaxf(mx, __shfl_xor(mx, 32, 64));
    float sm = 0.f;
#pragma unroll
    for (int mi = 0; mi < 2; ++mi)
#pragma unroll
      for (int r = 0; r < 16; ++r) {
        float e = __expf(st[mi][r] - mx);
        st[mi][r] = e;
        sm += e;
      }
    sm += __shfl_xor(sm, 32, 64);
    const float rinv = 1.f / sm;
#pragma unroll
    for (int mi = 0; mi < 2; ++mi)
#pragma unroll
      for (int r = 0; r < 16; ++r) st[mi][r] *= rinv;

    f32x16 acc = (f32x16)(0.f);
#pragma unroll
    for (int kt = 0; kt < 4; ++kt) {
      const int mi = kt >> 1, b8 = (kt & 1) * 8;
      unsigned q0l = cvtpk(st[mi][b8 + 0], st[mi][b8 + 1]);
      unsigned q0h = cvtpk(st[mi][b8 + 2], st[mi][b8 + 3]);
      unsigned q1l = cvtpk(st[mi][b8 + 4], st[mi][b8 + 5]);
      unsigned q1h = cvtpk(st[mi][b8 + 6], st[mi][b8 + 7]);
      unsigned sl = h5 ? q0l : q1l, sh = h5 ? q0h : q1h;
      unsigned kl = h5 ? q1l : q0l, kh = h5 ? q1h : q0h;
      unsigned rl = (unsigned)__shfl_xor((int)sl, 32, 64);
      unsigned rh = (unsigned)__shfl_xor((int)sh, 32, 64);
      u32x4 fr;
      fr[0] = h5 ? rl : kl;
      fr[1] = h5 ? rh : kh;
      fr[2] = h5 ? kl : rl;
      fr[3] = h5 ? kh : rh;
      acc = mfma32(__builtin_bit_cast(bf16x8, fr), vf[kt], acc);
    }
#pragma unroll
    for (int r = 0; r < 16; ++r) {
      int query = 32 * ni + (r & 3) + 8 * (r >> 2) + 4 * h5;
      if (ni == 0 || query < 49)
        out[(tokbase + query) * 384 + h * 32 + l31] = f2b(acc[r]);
    }
  }
}

// ---------------------------------------------------------------- launch
extern "C" void kernel_launch(void* const* d_in, const int* in_sizes, int n_in,
                              void* d_out, int out_size, void* d_ws,
                              size_t ws_size, hipStream_t stream) {
  const float* x = (const float*)d_in[0];
  const float* n1g = (const float*)d_in[1];
  const float* n1b = (const float*)d_in[2];
  const float* qkvw = (const float*)d_in[3];
  const float* qkvb = (const float*)d_in[4];
  const float* projw = (const float*)d_in[5];
  const float* projb = (const float*)d_in[6];
  const float* rpb = (const float*)d_in[7];
  const float* n2g = (const float*)d_in[8];
  const float* n2b = (const float*)d_in[9];
  const float* fc1w = (const float*)d_in[10];
  const float* fc1b = (const float*)d_in[11];
  const float* fc2w = (const float*)d_in[12];
  const float* fc2b = (const float*)d_in[13];
  float* out = (float*)d_out;

  char* ws = (char*)d_ws;
  short* w_qkvT = (short*)(ws + 0);            // 884736 B
  short* w_projT = (short*)(ws + 884736);      // 294912 B
  short* w_fc1T = (short*)(ws + 1179648);      // 1179648 B
  short* w_fc2T = (short*)(ws + 2359296);      // 1179648 B
  float* w_qb = (float*)(ws + 3538944);        // 4608 B
  float* tbl = (float*)(ws + 3543552);         // 786432 B
  const size_t o_qkv = 4329984;
  short* qkvbuf = (short*)(ws + o_qkv);        // 462422016 B
  const size_t o_hwin = o_qkv + 462422016ull;
  short* hwin = (short*)(ws + o_hwin);         // 154140672 B
  short* fc1c = hwin;  // MLP slab overlays hwin (dead after proj)
  short* h2 = qkvbuf;  // LN2 out overlays qkv buffer (dead after attn)

  const float qscale = 0.17677669529663687f;

  convT_k<<<(442368 + 255) / 256, 256, 0, stream>>>(qkvw, w_qkvT, 384, 1152, 384, qscale);
  convT_k<<<(147456 + 255) / 256, 256, 0, stream>>>(projw, w_projT, 384, 384, 0, 1.f);
  convT_k<<<(589824 + 255) / 256, 256, 0, stream>>>(fc1w, w_fc1T, 384, 1536, 0, 1.f);
  convT_k<<<(589824 + 255) / 256, 256, 0, stream>>>(fc2w, w_fc2T, 1536, 384, 0, 1.f);
  scale_bias_k<<<5, 256, 0, stream>>>(qkvb, w_qb, 1152, 384, qscale);
  biasmask_k<<<768, 256, 0, stream>>>(rpb, tbl);

  ln1_k<<<50176, 256, 0, stream>>>(x, n1g, n1b, hwin);
  // K=384 GEMMs: geometry B (256x128, BK=32, wave 64x64)
  gemm_qkv_k<<<dim3(9, 784), 512, 0, stream>>>(hwin, 384, w_qkvT, 384, w_qb,
                                               384, qkvbuf, 1152, nullptr,
                                               nullptr);
  attn_k<<<12288, 256, 0, stream>>>(qkvbuf, tbl, hwin);
  gemm_proj_k<<<dim3(3, 784), 512, 0, stream>>>(hwin, 384, w_projT, 384,
                                                projb, 384, nullptr, 384, out,
                                                x);
  ln2_k<<<50176, 256, 0, stream>>>(out, n2g, n2b, h2);
  // MLP over 4 M-slabs of 50176 rows: fc1 geometry B (K=384), fc2
  // geometry A (K=1536). Slab L3-resident; out RMW'd once.
  for (int s = 0; s < 4; ++s) {
    const size_t ro = (size_t)s * 50176;
    gemm_fc1_k<<<dim3(12, 196), 512, 0, stream>>>(
        h2 + ro * 384, 384, w_fc1T, 384, fc1b, 384, fc1c, 1536, nullptr,
        nullptr);
    gemm_fc2_k<<<dim3(3, 392), 512, 0, stream>>>(
        fc1c, 1536, w_fc2T, 1536, fc2b, 1536, nullptr, 384, out + ro * 384,
        nullptr);
  }
}